// Round 9
// baseline (1184.430 us; speedup 1.0000x reference)
//
#include <hip/hip_runtime.h>
#include <math.h>

#define TT 512
#define DD 128
#define MM 512
#define EE 512
#define NTAGS 74
#define GH 64
#define LH 256

typedef _Float16 half_t;
typedef _Float16 v2h __attribute__((ext_vector_type(2)));
typedef _Float16 v8h __attribute__((ext_vector_type(8)));
typedef _Float16 v16h __attribute__((ext_vector_type(16)));
typedef int v4i __attribute__((ext_vector_type(4)));
typedef float vf4 __attribute__((ext_vector_type(4)));

__device__ __forceinline__ float fdot2f(v2h a, v2h b, float c) {
#if __has_builtin(__builtin_amdgcn_fdot2)
    return __builtin_amdgcn_fdot2(a, b, c, false);
#else
    return c + (float)a[0] * (float)b[0] + (float)a[1] * (float)b[1];
#endif
}

__device__ __forceinline__ int sdot4(int a, int b, int c) {
#if __has_builtin(__builtin_amdgcn_sdot4)
    return __builtin_amdgcn_sdot4(a, b, c, false);
#else
    return c + ((a << 24) >> 24) * ((b << 24) >> 24)
             + ((a << 16) >> 24) * ((b << 16) >> 24)
             + ((a << 8) >> 24) * ((b << 8) >> 24)
             + (a >> 24) * (b >> 24);
#endif
}

__device__ __forceinline__ float sigf(float x) { return 1.f / (1.f + __expf(-x)); }
__device__ __forceinline__ float tanhfast(float x) { return 1.f - 2.f / (__expf(2.f * x) + 1.f); }

// LDS barrier: drain this wave's DS ops, then workgroup barrier.
__device__ __forceinline__ void lds_barrier() {
    asm volatile("s_waitcnt lgkmcnt(0)" ::: "memory");
    __builtin_amdgcn_s_barrier();
}
__device__ __forceinline__ void wait_vmcnt0() {
    asm volatile("s_waitcnt vmcnt(0)" ::: "memory");
}

// Async global->LDS copy, 16 B per lane (vmcnt-tracked by construction;
// LDS dest must be wave-uniform-base + lane*16 -- our linear mapping is).
typedef const __attribute__((address_space(1))) void* as1cv;
typedef __attribute__((address_space(3))) void* as3v;
__device__ __forceinline__ void gload_lds16(const float* g, float* l) {
    __builtin_amdgcn_global_load_lds((as1cv)g, (as3v)l, 16, 0, 0);
}

// True global_store_dwordx4 via ext_vector (primitive store compiles with
// address_space(1); HIP float4 is a class whose operator= cannot).
typedef __attribute__((address_space(1))) vf4 g4_t;
__device__ __forceinline__ void gstore4(float* p, float a, float b, float c, float d) {
    vf4 v = {a, b, c, d};
    *(g4_t*)p = v;
}

// DPP cross-lane adds (pure VALU, DS pipe stays free).
__device__ __forceinline__ int preduce_i(int x) {           // pair (xor 1)
    x += __builtin_amdgcn_mov_dpp(x, 0xB1, 0xF, 0xF, true);
    return x;
}
__device__ __forceinline__ float qreduce_f(float x) {       // quad (xor 1, xor 2)
    x += __int_as_float(__builtin_amdgcn_mov_dpp(__float_as_int(x), 0xB1, 0xF, 0xF, true));
    x += __int_as_float(__builtin_amdgcn_mov_dpp(__float_as_int(x), 0x4E, 0xF, 0xF, true));
    return x;
}

// 16 f32 -> v16h (SSA value, 8 VGPRs)
__device__ __forceinline__ v16h load16(const float* p) {
    float4 x0 = ((const float4*)p)[0];
    float4 x1 = ((const float4*)p)[1];
    float4 x2 = ((const float4*)p)[2];
    float4 x3 = ((const float4*)p)[3];
    v16h r;
    r[0] = (half_t)x0.x; r[1] = (half_t)x0.y; r[2] = (half_t)x0.z; r[3] = (half_t)x0.w;
    r[4] = (half_t)x1.x; r[5] = (half_t)x1.y; r[6] = (half_t)x1.z; r[7] = (half_t)x1.w;
    r[8] = (half_t)x2.x; r[9] = (half_t)x2.y; r[10] = (half_t)x2.z; r[11] = (half_t)x2.w;
    r[12] = (half_t)x3.x; r[13] = (half_t)x3.y; r[14] = (half_t)x3.z; r[15] = (half_t)x3.w;
    return r;
}

#define OPAQUE3(a, b, c) asm volatile("" : "+v"(a), "+v"(b), "+v"(c))
#define OPAQUE4(a, b, c, d) asm volatile("" : "+v"(a), "+v"(b), "+v"(c), "+v"(d))

__device__ __forceinline__ void dot16(const v16h& w, const v8h& h0, const v8h& h1,
                                      float& x0, float& x1) {
    x0 = fdot2f(v2h{w[0], w[1]}, v2h{h0[0], h0[1]}, x0);
    x1 = fdot2f(v2h{w[2], w[3]}, v2h{h0[2], h0[3]}, x1);
    x0 = fdot2f(v2h{w[4], w[5]}, v2h{h0[4], h0[5]}, x0);
    x1 = fdot2f(v2h{w[6], w[7]}, v2h{h0[6], h0[7]}, x1);
    x0 = fdot2f(v2h{w[8], w[9]}, v2h{h1[0], h1[1]}, x0);
    x1 = fdot2f(v2h{w[10], w[11]}, v2h{h1[2], h1[3]}, x1);
    x0 = fdot2f(v2h{w[12], w[13]}, v2h{h1[4], h1[5]}, x0);
    x1 = fdot2f(v2h{w[14], w[15]}, v2h{h1[6], h1[7]}, x1);
}

__device__ __forceinline__ int pack4(int b0, int b1, int b2, int b3) {
    return (b0 & 0xff) | ((b1 & 0xff) << 8) | ((b2 & 0xff) << 16) | (b3 << 24);
}

// quantize 16 consecutive f32 weights -> 16 int8 packed in v4i
__device__ __forceinline__ v4i quant16(const float* p, float inv_s) {
    float4 x0 = ((const float4*)p)[0];
    float4 x1 = ((const float4*)p)[1];
    float4 x2 = ((const float4*)p)[2];
    float4 x3 = ((const float4*)p)[3];
    v4i r;
    r.x = pack4(__float2int_rn(x0.x * inv_s), __float2int_rn(x0.y * inv_s),
                __float2int_rn(x0.z * inv_s), __float2int_rn(x0.w * inv_s));
    r.y = pack4(__float2int_rn(x1.x * inv_s), __float2int_rn(x1.y * inv_s),
                __float2int_rn(x1.z * inv_s), __float2int_rn(x1.w * inv_s));
    r.z = pack4(__float2int_rn(x2.x * inv_s), __float2int_rn(x2.y * inv_s),
                __float2int_rn(x2.z * inv_s), __float2int_rn(x2.w * inv_s));
    r.w = pack4(__float2int_rn(x3.x * inv_s), __float2int_rn(x3.y * inv_s),
                __float2int_rn(x3.z * inv_s), __float2int_rn(x3.w * inv_s));
    return r;
}

__device__ __forceinline__ float rowmax128(const float* p) {
    float m = 0.f;
#pragma unroll 8
    for (int k = 0; k < 128; k += 4) {
        float4 a = *(const float4*)(p + k);
        m = fmaxf(m, fmaxf(fmaxf(fabsf(a.x), fabsf(a.y)), fmaxf(fabsf(a.z), fabsf(a.w))));
    }
    return m;
}

// ---------------- K1: dots[m] = <memory[m], u> ----------------
__global__ __launch_bounds__(256) void k_dots(const float* __restrict__ mem,
                                              const float* __restrict__ u,
                                              float* __restrict__ dots) {
    int m = blockIdx.x;
    const float4* m4 = (const float4*)(mem + (size_t)m * TT * DD);
    const float4* u4 = (const float4*)u;
    float acc = 0.f;
#pragma unroll 4
    for (int it = 0; it < (TT * DD / 4) / 256; ++it) {
        int i = it * 256 + threadIdx.x;
        float4 a = m4[i], b = u4[i];
        acc += a.x * b.x + a.y * b.y + a.z * b.z + a.w * b.w;
    }
    for (int off = 32; off; off >>= 1) acc += __shfl_down(acc, off, 64);
    __shared__ float red[4];
    int w = threadIdx.x >> 6, l = threadIdx.x & 63;
    if (l == 0) red[w] = acc;
    __syncthreads();
    if (threadIdx.x == 0) dots[m] = red[0] + red[1] + red[2] + red[3];
}

// ---------------- K2: p = softmax(dots) ----------------
__global__ __launch_bounds__(512) void k_softmax_p(const float* __restrict__ dots,
                                                   float* __restrict__ p) {
    int tid = threadIdx.x;
    float v = dots[tid];
    float mx = v;
    for (int off = 32; off; off >>= 1) mx = fmaxf(mx, __shfl_down(mx, off, 64));
    __shared__ float red[8];
    __shared__ float bm, bs;
    int w = tid >> 6, l = tid & 63;
    if (l == 0) red[w] = mx;
    __syncthreads();
    if (tid == 0) {
        float t = red[0];
        for (int i = 1; i < 8; ++i) t = fmaxf(t, red[i]);
        bm = t;
    }
    __syncthreads();
    float e = __expf(v - bm);
    float sm = e;
    for (int off = 32; off; off >>= 1) sm += __shfl_down(sm, off, 64);
    if (l == 0) red[w] = sm;
    __syncthreads();
    if (tid == 0) {
        float t = 0.f;
        for (int i = 0; i < 8; ++i) t += red[i];
        bs = t;
    }
    __syncthreads();
    p[tid] = e / bs;
}

// ---------------- K3: Mbar = sum_m p[m]*memory[m] ----------------
__global__ __launch_bounds__(128) void k_wsum(const float* __restrict__ mem,
                                              const float* __restrict__ p,
                                              float* __restrict__ Mbar) {
    __shared__ float pl[MM];
    for (int i = threadIdx.x; i < MM; i += 128) pl[i] = p[i];
    __syncthreads();
    int i4 = blockIdx.x * 128 + threadIdx.x;
    const float4* m4 = (const float4*)mem;
    float4 acc = {0.f, 0.f, 0.f, 0.f};
#pragma unroll 4
    for (int m = 0; m < MM; ++m) {
        float pm = pl[m];
        float4 a = m4[(size_t)m * (TT * DD / 4) + i4];
        acc.x += pm * a.x; acc.y += pm * a.y; acc.z += pm * a.z; acc.w += pm * a.w;
    }
    ((float4*)Mbar)[i4] = acc;
}

// ---------------- K4: G = Mbar@W1.T + u@W2.T + b_ff ----------------
__global__ __launch_bounds__(128) void k_G(const float* __restrict__ Mbar,
                                           const float* __restrict__ u,
                                           const float* __restrict__ Wff,
                                           const float* __restrict__ bff,
                                           float* __restrict__ G) {
    int t = blockIdx.x, d = threadIdx.x;
    __shared__ __align__(16) float Ml[DD], ul[DD];
    Ml[d] = Mbar[t * DD + d];
    ul[d] = u[t * DD + d];
    __syncthreads();
    const float* wr = Wff + (size_t)d * 2 * DD;
    float a0 = 0.f, a1 = 0.f;
#pragma unroll 4
    for (int k = 0; k < DD; ++k) {
        a0 += Ml[k] * wr[k];
        a1 += ul[k] * wr[DD + k];
    }
    G[t * DD + d] = a0 + a1 + bff[d];
}

// ---------------- K5: GRU input projections (gate-interleaved layout) -------
__global__ __launch_bounds__(384) void k_gru_gi(const float* __restrict__ G,
                                                const float* __restrict__ Wf,
                                                const float* __restrict__ bf,
                                                const float* __restrict__ Wb,
                                                const float* __restrict__ bb,
                                                float* __restrict__ gi) {
    int t = blockIdx.x;
    __shared__ __align__(16) float Gl[DD];
    if (threadIdx.x < DD) Gl[threadIdx.x] = G[t * DD + threadIdx.x];
    __syncthreads();
    int r = threadIdx.x;
    int dir = r >= 192;
    int rr = dir ? r - 192 : r;
    int gate = rr >> 6, unit = rr & 63;
    const float* w = (dir ? Wb : Wf) + (size_t)rr * DD;
    float b = (dir ? bb : bf)[rr];
    float a0 = 0.f, a1 = 0.f;
#pragma unroll 4
    for (int k = 0; k < DD; k += 2) {
        a0 += Gl[k] * w[k];
        a1 += Gl[k + 1] * w[k + 1];
    }
    gi[((size_t)dir * TT + t) * 256 + unit * 4 + gate] = a0 + a1 + b;
}

// ---------------- K6: sequential BiGRU, 256 threads (4 lanes/unit) ----------
// gi staged through LDS in 8-step double-buffered chunks via
// global_load_lds (vmcnt-only): NO per-step global traffic, one vmcnt(0)
// per 8 steps fully covered by compute. Per step gq = one broadcast
// ds_read_b128 issued at step top (latency hides under the dot chain).
// Weights in 3 v16h regs; DPP quad reduce; hl double-buffered; one
// lds_barrier/step; hbufT stores via address_space(1) (never flat).
__global__ __launch_bounds__(256) void k_gru_seq(const float* __restrict__ Whh_f,
                                                 const float* __restrict__ bhh_f,
                                                 const float* __restrict__ Whh_b,
                                                 const float* __restrict__ bhh_b,
                                                 const float* __restrict__ gi,
                                                 float* __restrict__ hbufT) {
    int dir = blockIdx.x;
    int tid = threadIdx.x;
    int u = tid >> 2;  // 0..63
    int q = tid & 3;   // 16-col slice
    const float* Whh = dir ? Whh_b : Whh_f;
    const float* bhh = dir ? bhh_b : bhh_f;
    v16h wr = load16(Whh + (size_t)u * 64 + q * 16);
    v16h wz = load16(Whh + (size_t)(64 + u) * 64 + q * 16);
    v16h wn = load16(Whh + (size_t)(128 + u) * 64 + q * 16);
    OPAQUE3(wr, wz, wn);
    float bh_r = bhh[u], bh_z = bhh[64 + u], bh_n = bhh[128 + u];

    const float* gdir = gi + (size_t)dir * TT * 256;

    __shared__ __align__(16) float gbuf[2][8][256];   // 16 KB staging
    __shared__ __align__(16) half_t hl[2][64];

    // stage one 8-step chunk (8 rows x 1 KB = 8 KB; 2 x 16 B per thread)
#define GSTAGE(C, B) { \
    int tb_ = dir ? (TT - 8 * ((C) + 1)) : (8 * (C)); \
    const float* gs_ = gdir + (size_t)tb_ * 256; \
    gload_lds16(gs_ + (tid) * 4, &gbuf[B][0][0] + (tid) * 4); \
    gload_lds16(gs_ + (256 + tid) * 4, &gbuf[B][0][0] + (256 + tid) * 4); }

    GSTAGE(0, 0);
    if (tid < 64) hl[0][tid] = (half_t)0.f;
    float h = 0.f;
    wait_vmcnt0();
    lds_barrier();

    float hs0 = 0.f, hs1 = 0.f, hs2 = 0.f, hs3 = 0.f;
#define GSTEP(J, HS) { \
    float4 gq = *(const float4*)&gbuf[buf][dir ? 7 - (J) : (J)][u * 4]; \
    const v8h* hv_ = (const v8h*)&hl[(J) & 1][q * 16]; \
    v8h h0_ = hv_[0], h1_ = hv_[1]; \
    float ar0 = 0.f, ar1 = 0.f, az0 = 0.f, az1 = 0.f, an0 = 0.f, an1 = 0.f; \
    dot16(wr, h0_, h1_, ar0, ar1); \
    dot16(wz, h0_, h1_, az0, az1); \
    dot16(wn, h0_, h1_, an0, an1); \
    float srd = qreduce_f(ar0 + ar1); \
    float szd = qreduce_f(az0 + az1); \
    float snd = qreduce_f(an0 + an1); \
    float r_ = sigf(gq.x + srd + bh_r); \
    float z_ = sigf(gq.y + szd + bh_z); \
    float n_ = tanhfast(gq.z + r_ * (snd + bh_n)); \
    h = (1.f - z_) * n_ + z_ * h; \
    if (q == 0) hl[((J) + 1) & 1][u] = (half_t)h; \
    HS = h; \
    if ((J) == 7) wait_vmcnt0(); \
    lds_barrier(); }

#define GSTORE(S4) { \
    if (q == 0) { \
        if (dir == 0) gstore4(hbufT + (size_t)(dir * 64 + u) * TT + (S4), hs0, hs1, hs2, hs3); \
        else          gstore4(hbufT + (size_t)(dir * 64 + u) * TT + (TT - 4 - (S4)), hs3, hs2, hs1, hs0); } }

    for (int c = 0; c < TT / 8; ++c) {
        int buf = c & 1;
        if (c + 1 < TT / 8) GSTAGE(c + 1, buf ^ 1);
        GSTEP(0, hs0); GSTEP(1, hs1); GSTEP(2, hs2); GSTEP(3, hs3);
        GSTORE(8 * c);
        GSTEP(4, hs0); GSTEP(5, hs1); GSTEP(6, hs2); GSTEP(7, hs3);
        GSTORE(8 * c + 4);
    }
#undef GSTEP
#undef GSTORE
#undef GSTAGE
}

// ---------------- K7: x = embed + (u + h)@W_k.T + b_k ----------------
__global__ __launch_bounds__(512) void k_x(const float* __restrict__ u,
                                           const float* __restrict__ hbufT,
                                           const float* __restrict__ Wk,
                                           const float* __restrict__ bk,
                                           const float* __restrict__ embed,
                                           float* __restrict__ x) {
    int t = blockIdx.x, e = threadIdx.x;
    __shared__ __align__(16) float sl[DD];
    if (e < DD) sl[e] = u[t * DD + e] + hbufT[(size_t)e * TT + t];
    __syncthreads();
    const float* wr = Wk + (size_t)e * DD;
    float a0 = 0.f, a1 = 0.f;
#pragma unroll 4
    for (int k = 0; k < DD; k += 2) {
        a0 += sl[k] * wr[k];
        a1 += sl[k + 1] * wr[k + 1];
    }
    x[t * EE + e] = embed[t * EE + e] + a0 + a1 + bk[e];
}

// ---------------- K8: LSTM input projections (gate-interleaved layout) ------
__global__ __launch_bounds__(1024) void k_lstm_gi(const float* __restrict__ x,
                                                  const float* __restrict__ Wf,
                                                  const float* __restrict__ bf,
                                                  const float* __restrict__ Wb,
                                                  const float* __restrict__ bb,
                                                  float* __restrict__ gi) {
    int dir = blockIdx.y;
    int t0 = blockIdx.x * 8;
    __shared__ __align__(16) float xl[8 * EE];
    for (int i = threadIdx.x; i < 8 * EE; i += 1024) xl[i] = x[(size_t)t0 * EE + i];
    __syncthreads();
    int r = threadIdx.x;
    int gate = r >> 8, un = r & 255;
    const float* W = dir ? Wb : Wf;
    const float* bi = dir ? bb : bf;
    const float* wr = W + (size_t)r * EE;
    float b = bi[r];
    float acc[8];
#pragma unroll
    for (int uu = 0; uu < 8; ++uu) acc[uu] = b;
    for (int k = 0; k < EE; k += 4) {
        float4 wv = *(const float4*)(wr + k);
#pragma unroll
        for (int uu = 0; uu < 8; ++uu) {
            float4 xv = *(const float4*)(&xl[uu * EE + k]);
            acc[uu] += wv.x * xv.x + wv.y * xv.y + wv.z * xv.z + wv.w * xv.w;
        }
    }
#pragma unroll
    for (int uu = 0; uu < 8; ++uu)
        gi[((size_t)dir * TT + (t0 + uu)) * 1024 + un * 4 + gate] = acc[uu];
}

// ---------------- K9: sequential BiLSTM, 512 threads (2 lanes/unit) ---------
// As R7 (best measured config) plus: gi staged through LDS in 8-step
// double-buffered chunks via global_load_lds (vmcnt-only; 32 KB/chunk,
// 4 x 16 B per thread) -> NO per-step global traffic, one vmcnt(0) per 8
// steps covered by ~8 steps of compute. Per step gq = one broadcast
// ds_read_b128 at step top. comb stores via address_space(1).
__global__ __launch_bounds__(512) __attribute__((amdgpu_waves_per_eu(2, 2)))
void k_lstm_seq(const float* __restrict__ Whh_f,
                const float* __restrict__ bhh_f,
                const float* __restrict__ Whh_b,
                const float* __restrict__ bhh_b,
                const float* __restrict__ gi,
                float* __restrict__ combT) {
    int dir = blockIdx.x;
    int tid = threadIdx.x;
    int u = tid >> 1;      // 0..255
    int half = tid & 1;    // 128-col half
    const float* Whh = dir ? Whh_b : Whh_f;
    const float* bhh = dir ? bhh_b : bhh_f;

    __shared__ __align__(16) float gbuf[2][8][1024];  // 64 KB staging
    __shared__ __align__(16) int hq[2][64];           // 2 x 256 int8 h

    const float* ri = Whh + (size_t)u * 256 + half * 128;
    const float* rf = ri + 256 * 256;
    const float* rg = ri + 512 * 256;
    const float* ro = ri + 768 * 256;

    float mi = rowmax128(ri); mi = fmaxf(mi, __shfl_xor(mi, 1, 64));
    float mf = rowmax128(rf); mf = fmaxf(mf, __shfl_xor(mf, 1, 64));
    float mg = rowmax128(rg); mg = fmaxf(mg, __shfl_xor(mg, 1, 64));
    float mo = rowmax128(ro); mo = fmaxf(mo, __shfl_xor(mo, 1, 64));
    float fs_i = mi / 16129.f, fs_f = mf / 16129.f, fs_g = mg / 16129.f, fs_o = mo / 16129.f;

    float inv_i = 127.f / mi, inv_f = 127.f / mf, inv_g = 127.f / mg, inv_o = 127.f / mo;
#define DECLG(P, ptr, inv)                                                        \
    v4i P##0 = quant16((ptr), (inv)),       P##1 = quant16((ptr) + 16, (inv)),    \
        P##2 = quant16((ptr) + 32, (inv)),  P##3 = quant16((ptr) + 48, (inv)),    \
        P##4 = quant16((ptr) + 64, (inv)),  P##5 = quant16((ptr) + 80, (inv)),    \
        P##6 = quant16((ptr) + 96, (inv)),  P##7 = quant16((ptr) + 112, (inv));   \
    OPAQUE4(P##0, P##1, P##2, P##3);                                              \
    OPAQUE4(P##4, P##5, P##6, P##7)

    DECLG(wi, ri, inv_i);
    DECLG(wf, rf, inv_f);
    DECLG(wg, rg, inv_g);
    DECLG(wo, ro, inv_o);
#undef DECLG

    float bh_i = bhh[u], bh_f = bhh[256 + u], bh_g = bhh[512 + u], bh_o = bhh[768 + u];

    const float* gdir = gi + (size_t)dir * TT * 1024;

    // stage one 8-step chunk (8 rows x 4 KB = 32 KB; 4 x 16 B per thread)
#define LSTAGE(C, B) { \
    int tb_ = dir ? (TT - 8 * ((C) + 1)) : (8 * (C)); \
    const float* gs_ = gdir + (size_t)tb_ * 1024; \
    gload_lds16(gs_ + (tid) * 4, &gbuf[B][0][0] + (tid) * 4); \
    gload_lds16(gs_ + (512 + tid) * 4, &gbuf[B][0][0] + (512 + tid) * 4); \
    gload_lds16(gs_ + (1024 + tid) * 4, &gbuf[B][0][0] + (1024 + tid) * 4); \
    gload_lds16(gs_ + (1536 + tid) * 4, &gbuf[B][0][0] + (1536 + tid) * 4); }

    LSTAGE(0, 0);
    if (tid < 64) hq[0][tid] = 0;
    float c_state = 0.f;
    wait_vmcnt0();
    lds_barrier();

    float hs0 = 0.f, hs1 = 0.f, hs2 = 0.f, hs3 = 0.f;
#define LD1(P, C, HV, A0, A1) \
    A0 = sdot4((P##C).x, HV.x, A0); A1 = sdot4((P##C).y, HV.y, A1); \
    A0 = sdot4((P##C).z, HV.z, A0); A1 = sdot4((P##C).w, HV.w, A1)
#define LDOT8(P, A0, A1) \
    LD1(P, 0, h0_, A0, A1); LD1(P, 1, h1_, A0, A1); \
    LD1(P, 2, h2_, A0, A1); LD1(P, 3, h3_, A0, A1); \
    LD1(P, 4, h4_, A0, A1); LD1(P, 5, h5_, A0, A1); \
    LD1(P, 6, h6_, A0, A1); LD1(P, 7, h7_, A0, A1)

#define LSTEP(J, HS) { \
    float4 gq = *(const float4*)&gbuf[buf][dir ? 7 - (J) : (J)][u * 4]; \
    const v4i* hb_ = (const v4i*)&hq[(J) & 1][half * 32]; \
    v4i h0_ = hb_[0], h1_ = hb_[1], h2_ = hb_[2], h3_ = hb_[3]; \
    v4i h4_ = hb_[4], h5_ = hb_[5], h6_ = hb_[6], h7_ = hb_[7]; \
    int ai0 = 0, ai1 = 0, af0 = 0, af1 = 0, ag0 = 0, ag1 = 0, ao0 = 0, ao1 = 0; \
    LDOT8(wi, ai0, ai1); \
    LDOT8(wf, af0, af1); \
    LDOT8(wg, ag0, ag1); \
    LDOT8(wo, ao0, ao1); \
    int ai_ = preduce_i(ai0 + ai1); \
    int af_ = preduce_i(af0 + af1); \
    int ag_ = preduce_i(ag0 + ag1); \
    int ao_ = preduce_i(ao0 + ao1); \
    float iv = sigf((float)ai_ * fs_i + bh_i + gq.x); \
    float fv = sigf((float)af_ * fs_f + bh_f + gq.y); \
    float gv = tanhfast((float)ag_ * fs_g + bh_g + gq.z); \
    float ov = sigf((float)ao_ * fs_o + bh_o + gq.w); \
    c_state = fv * c_state + iv * gv; \
    HS = ov * tanhfast(c_state); \
    if (half == 0) ((signed char*)hq[((J) + 1) & 1])[u] = (signed char)__float2int_rn(HS * 127.f); \
    if ((J) == 7) wait_vmcnt0(); \
    lds_barrier(); }

#define LSTORE(S4) { \
    if (half == 0) { \
        if (dir == 0) gstore4(combT + (size_t)(dir * 256 + u) * TT + (S4), hs0, hs1, hs2, hs3); \
        else          gstore4(combT + (size_t)(dir * 256 + u) * TT + (TT - 4 - (S4)), hs3, hs2, hs1, hs0); } }

    for (int c = 0; c < TT / 8; ++c) {
        int buf = c & 1;
        if (c + 1 < TT / 8) LSTAGE(c + 1, buf ^ 1);
        LSTEP(0, hs0); LSTEP(1, hs1); LSTEP(2, hs2); LSTEP(3, hs3);
        LSTORE(8 * c);
        LSTEP(4, hs0); LSTEP(5, hs1); LSTEP(6, hs2); LSTEP(7, hs3);
        LSTORE(8 * c + 4);
    }
#undef LSTEP
#undef LSTORE
#undef LSTAGE
#undef LDOT8
#undef LD1
}

// ---------------- K10: logits + softmax ----------------
__global__ __launch_bounds__(128) void k_out(const float* __restrict__ combT,
                                             const float* __restrict__ Wout,
                                             const float* __restrict__ bout,
                                             float* __restrict__ out) {
    int t = blockIdx.x;
    __shared__ __align__(16) float cl[EE];
    __shared__ float ll[NTAGS];
    __shared__ float mred, sred;
    for (int i = threadIdx.x; i < EE; i += 128) cl[i] = combT[(size_t)i * TT + t];
    __syncthreads();
    int e = threadIdx.x;
    if (e < NTAGS) {
        const float* wr = Wout + (size_t)e * EE;
        float a0 = 0.f, a1 = 0.f;
#pragma unroll 4
        for (int k = 0; k < EE; k += 2) {
            a0 += cl[k] * wr[k];
            a1 += cl[k + 1] * wr[k + 1];
        }
        ll[e] = a0 + a1 + bout[e];
    }
    __syncthreads();
    if (threadIdx.x == 0) {
        float m = ll[0];
        for (int i = 1; i < NTAGS; ++i) m = fmaxf(m, ll[i]);
        float ss = 0.f;
        for (int i = 0; i < NTAGS; ++i) ss += __expf(ll[i] - m);
        mred = m;
        sred = ss;
    }
    __syncthreads();
    if (e < NTAGS) out[t * NTAGS + e] = __expf(ll[e] - mred) / sred;
}

// ---------------- workspace layout (floats) ----------------
#define OFF_DOTS  ((size_t)0)
#define OFF_P     ((size_t)512)
#define OFF_MBAR  ((size_t)1024)
#define OFF_G     ((size_t)66560)
#define OFF_HBUF  ((size_t)328704)   // hbufT [128][512]
#define OFF_X     ((size_t)394240)   // [512][512]
#define OFF_GIL   ((size_t)656384)   // [2][512][1024]
#define OFF_COMB  ((size_t)1704960)  // combT [512][512]
#define OFF_GIG   OFF_COMB           // giG [2][512][256] (disjoint lifetime)

extern "C" void kernel_launch(void* const* d_in, const int* in_sizes, int n_in,
                              void* d_out, int out_size, void* d_ws, size_t ws_size,
                              hipStream_t stream) {
    const float* memory = (const float*)d_in[0];
    const float* u      = (const float*)d_in[1];
    const float* embed  = (const float*)d_in[2];
    const float* W_ff   = (const float*)d_in[3];
    const float* b_ff   = (const float*)d_in[4];
    const float* gWih_f = (const float*)d_in[5];
    const float* gWhh_f = (const float*)d_in[6];
    const float* gbih_f = (const float*)d_in[7];
    const float* gbhh_f = (const float*)d_in[8];
    const float* gWih_b = (const float*)d_in[9];
    const float* gWhh_b = (const float*)d_in[10];
    const float* gbih_b = (const float*)d_in[11];
    const float* gbhh_b = (const float*)d_in[12];
    const float* W_k    = (const float*)d_in[13];
    const float* b_k    = (const float*)d_in[14];
    const float* lWih_f = (const float*)d_in[15];
    const float* lWhh_f = (const float*)d_in[16];
    const float* lbih_f = (const float*)d_in[17];
    const float* lbhh_f = (const float*)d_in[18];
    const float* lWih_b = (const float*)d_in[19];
    const float* lWhh_b = (const float*)d_in[20];
    const float* lbih_b = (const float*)d_in[21];
    const float* lbhh_b = (const float*)d_in[22];
    const float* W_out  = (const float*)d_in[23];
    const float* b_out  = (const float*)d_in[24];
    float* out = (float*)d_out;
    float* ws = (float*)d_ws;

    float* dots  = ws + OFF_DOTS;
    float* p     = ws + OFF_P;
    float* Mbar  = ws + OFF_MBAR;
    float* G     = ws + OFF_G;
    float* giG   = ws + OFF_GIG;
    float* hbufT = ws + OFF_HBUF;
    float* x     = ws + OFF_X;
    float* giL   = ws + OFF_GIL;
    float* combT = ws + OFF_COMB;

    k_dots<<<MM, 256, 0, stream>>>(memory, u, dots);
    k_softmax_p<<<1, MM, 0, stream>>>(dots, p);
    k_wsum<<<128, 128, 0, stream>>>(memory, p, Mbar);
    k_G<<<TT, DD, 0, stream>>>(Mbar, u, W_ff, b_ff, G);
    k_gru_gi<<<TT, 384, 0, stream>>>(G, gWih_f, gbih_f, gWih_b, gbih_b, giG);
    k_gru_seq<<<2, 256, 0, stream>>>(gWhh_f, gbhh_f, gWhh_b, gbhh_b, giG, hbufT);
    k_x<<<TT, EE, 0, stream>>>(u, hbufT, W_k, b_k, embed, x);
    k_lstm_gi<<<dim3(64, 2), 1024, 0, stream>>>(x, lWih_f, lbih_f, lWih_b, lbih_b, giL);
    k_lstm_seq<<<2, 512, 0, stream>>>(lWhh_f, lbhh_f, lWhh_b, lbhh_b, giL, combT);
    k_out<<<TT, 128, 0, stream>>>(combT, W_out, b_out, out);
}

// Round 10
// 1134.592 us; speedup vs baseline: 1.0439x; 1.0439x over previous
//
#include <hip/hip_runtime.h>
#include <math.h>

#define TT 512
#define DD 128
#define MM 512
#define EE 512
#define NTAGS 74
#define GH 64
#define LH 256

typedef _Float16 half_t;
typedef _Float16 v2h __attribute__((ext_vector_type(2)));
typedef _Float16 v8h __attribute__((ext_vector_type(8)));
typedef _Float16 v16h __attribute__((ext_vector_type(16)));
typedef int v4i __attribute__((ext_vector_type(4)));

__device__ __forceinline__ float fdot2f(v2h a, v2h b, float c) {
#if __has_builtin(__builtin_amdgcn_fdot2)
    return __builtin_amdgcn_fdot2(a, b, c, false);
#else
    return c + (float)a[0] * (float)b[0] + (float)a[1] * (float)b[1];
#endif
}

__device__ __forceinline__ int sdot4(int a, int b, int c) {
#if __has_builtin(__builtin_amdgcn_sdot4)
    return __builtin_amdgcn_sdot4(a, b, c, false);
#else
    return c + ((a << 24) >> 24) * ((b << 24) >> 24)
             + ((a << 16) >> 24) * ((b << 16) >> 24)
             + ((a << 8) >> 24) * ((b << 8) >> 24)
             + (a >> 24) * (b >> 24);
#endif
}

__device__ __forceinline__ float sigf(float x) { return 1.f / (1.f + __expf(-x)); }
__device__ __forceinline__ float tanhfast(float x) { return 1.f - 2.f / (__expf(2.f * x) + 1.f); }

// LDS barrier: drain this wave's DS ops, then workgroup barrier. No
// sched_barrier walls: "memory" clobber orders DS ops; scheduler keeps
// freedom to place vmcnt waits for gi prefetch loads. (R7 measured-best.)
__device__ __forceinline__ void lds_barrier() {
    asm volatile("s_waitcnt lgkmcnt(0)" ::: "memory");
    __builtin_amdgcn_s_barrier();
}

// DPP cross-lane adds (pure VALU, DS pipe stays free).
__device__ __forceinline__ int preduce_i(int x) {           // pair (xor 1)
    x += __builtin_amdgcn_mov_dpp(x, 0xB1, 0xF, 0xF, true);
    return x;
}
__device__ __forceinline__ float qreduce_f(float x) {       // quad (xor 1, xor 2)
    x += __int_as_float(__builtin_amdgcn_mov_dpp(__float_as_int(x), 0xB1, 0xF, 0xF, true));
    x += __int_as_float(__builtin_amdgcn_mov_dpp(__float_as_int(x), 0x4E, 0xF, 0xF, true));
    return x;
}

// 16 f32 -> v16h (SSA value, 8 VGPRs)
__device__ __forceinline__ v16h load16(const float* p) {
    float4 x0 = ((const float4*)p)[0];
    float4 x1 = ((const float4*)p)[1];
    float4 x2 = ((const float4*)p)[2];
    float4 x3 = ((const float4*)p)[3];
    v16h r;
    r[0] = (half_t)x0.x; r[1] = (half_t)x0.y; r[2] = (half_t)x0.z; r[3] = (half_t)x0.w;
    r[4] = (half_t)x1.x; r[5] = (half_t)x1.y; r[6] = (half_t)x1.z; r[7] = (half_t)x1.w;
    r[8] = (half_t)x2.x; r[9] = (half_t)x2.y; r[10] = (half_t)x2.z; r[11] = (half_t)x2.w;
    r[12] = (half_t)x3.x; r[13] = (half_t)x3.y; r[14] = (half_t)x3.z; r[15] = (half_t)x3.w;
    return r;
}

#define OPAQUE3(a, b, c) asm volatile("" : "+v"(a), "+v"(b), "+v"(c))
#define OPAQUE4(a, b, c, d) asm volatile("" : "+v"(a), "+v"(b), "+v"(c), "+v"(d))

__device__ __forceinline__ void dot16(const v16h& w, const v8h& h0, const v8h& h1,
                                      float& x0, float& x1) {
    x0 = fdot2f(v2h{w[0], w[1]}, v2h{h0[0], h0[1]}, x0);
    x1 = fdot2f(v2h{w[2], w[3]}, v2h{h0[2], h0[3]}, x1);
    x0 = fdot2f(v2h{w[4], w[5]}, v2h{h0[4], h0[5]}, x0);
    x1 = fdot2f(v2h{w[6], w[7]}, v2h{h0[6], h0[7]}, x1);
    x0 = fdot2f(v2h{w[8], w[9]}, v2h{h1[0], h1[1]}, x0);
    x1 = fdot2f(v2h{w[10], w[11]}, v2h{h1[2], h1[3]}, x1);
    x0 = fdot2f(v2h{w[12], w[13]}, v2h{h1[4], h1[5]}, x0);
    x1 = fdot2f(v2h{w[14], w[15]}, v2h{h1[6], h1[7]}, x1);
}

__device__ __forceinline__ int pack4(int b0, int b1, int b2, int b3) {
    return (b0 & 0xff) | ((b1 & 0xff) << 8) | ((b2 & 0xff) << 16) | (b3 << 24);
}

// quantize 16 consecutive f32 weights -> 16 int8 packed in v4i
__device__ __forceinline__ v4i quant16(const float* p, float inv_s) {
    float4 x0 = ((const float4*)p)[0];
    float4 x1 = ((const float4*)p)[1];
    float4 x2 = ((const float4*)p)[2];
    float4 x3 = ((const float4*)p)[3];
    v4i r;
    r.x = pack4(__float2int_rn(x0.x * inv_s), __float2int_rn(x0.y * inv_s),
                __float2int_rn(x0.z * inv_s), __float2int_rn(x0.w * inv_s));
    r.y = pack4(__float2int_rn(x1.x * inv_s), __float2int_rn(x1.y * inv_s),
                __float2int_rn(x1.z * inv_s), __float2int_rn(x1.w * inv_s));
    r.z = pack4(__float2int_rn(x2.x * inv_s), __float2int_rn(x2.y * inv_s),
                __float2int_rn(x2.z * inv_s), __float2int_rn(x2.w * inv_s));
    r.w = pack4(__float2int_rn(x3.x * inv_s), __float2int_rn(x3.y * inv_s),
                __float2int_rn(x3.z * inv_s), __float2int_rn(x3.w * inv_s));
    return r;
}

__device__ __forceinline__ float rowmax128(const float* p) {
    float m = 0.f;
#pragma unroll 8
    for (int k = 0; k < 128; k += 4) {
        float4 a = *(const float4*)(p + k);
        m = fmaxf(m, fmaxf(fmaxf(fabsf(a.x), fabsf(a.y)), fmaxf(fabsf(a.z), fabsf(a.w))));
    }
    return m;
}

// ---------------- K1: dots[m] = <memory[m], u> ----------------
__global__ __launch_bounds__(256) void k_dots(const float* __restrict__ mem,
                                              const float* __restrict__ u,
                                              float* __restrict__ dots) {
    int m = blockIdx.x;
    const float4* m4 = (const float4*)(mem + (size_t)m * TT * DD);
    const float4* u4 = (const float4*)u;
    float acc = 0.f;
#pragma unroll 4
    for (int it = 0; it < (TT * DD / 4) / 256; ++it) {
        int i = it * 256 + threadIdx.x;
        float4 a = m4[i], b = u4[i];
        acc += a.x * b.x + a.y * b.y + a.z * b.z + a.w * b.w;
    }
    for (int off = 32; off; off >>= 1) acc += __shfl_down(acc, off, 64);
    __shared__ float red[4];
    int w = threadIdx.x >> 6, l = threadIdx.x & 63;
    if (l == 0) red[w] = acc;
    __syncthreads();
    if (threadIdx.x == 0) dots[m] = red[0] + red[1] + red[2] + red[3];
}

// ---------------- K2: p = softmax(dots) ----------------
__global__ __launch_bounds__(512) void k_softmax_p(const float* __restrict__ dots,
                                                   float* __restrict__ p) {
    int tid = threadIdx.x;
    float v = dots[tid];
    float mx = v;
    for (int off = 32; off; off >>= 1) mx = fmaxf(mx, __shfl_down(mx, off, 64));
    __shared__ float red[8];
    __shared__ float bm, bs;
    int w = tid >> 6, l = tid & 63;
    if (l == 0) red[w] = mx;
    __syncthreads();
    if (tid == 0) {
        float t = red[0];
        for (int i = 1; i < 8; ++i) t = fmaxf(t, red[i]);
        bm = t;
    }
    __syncthreads();
    float e = __expf(v - bm);
    float sm = e;
    for (int off = 32; off; off >>= 1) sm += __shfl_down(sm, off, 64);
    if (l == 0) red[w] = sm;
    __syncthreads();
    if (tid == 0) {
        float t = 0.f;
        for (int i = 0; i < 8; ++i) t += red[i];
        bs = t;
    }
    __syncthreads();
    p[tid] = e / bs;
}

// ---------------- K3: partial[q] = sum_{m in chunk q} p[m]*memory[m] --------
// 4-way M-split: grid (128,4) = 512 blocks (vs 128) so the second 128-MB
// pass runs at full L3/HBM bandwidth. Deterministic (no atomics); k_G sums
// the 4 partials. Partials live in the giL slot (written much later).
__global__ __launch_bounds__(128) void k_wsum4(const float* __restrict__ mem,
                                               const float* __restrict__ p,
                                               float* __restrict__ partial) {
    int q = blockIdx.y;
    int m0 = q * 128;
    __shared__ float pl[128];
    if (threadIdx.x < 128) pl[threadIdx.x] = p[m0 + threadIdx.x];
    __syncthreads();
    int i4 = blockIdx.x * 128 + threadIdx.x;
    const float4* m4 = (const float4*)mem;
    float4 acc = {0.f, 0.f, 0.f, 0.f};
#pragma unroll 4
    for (int mm = 0; mm < 128; ++mm) {
        float pm = pl[mm];
        float4 a = m4[(size_t)(m0 + mm) * (TT * DD / 4) + i4];
        acc.x += pm * a.x; acc.y += pm * a.y; acc.z += pm * a.z; acc.w += pm * a.w;
    }
    ((float4*)(partial + (size_t)q * (TT * DD)))[i4] = acc;
}

// ---------------- K4: G = Mbar@W1.T + u@W2.T + b_ff ----------------
__global__ __launch_bounds__(128) void k_G(const float* __restrict__ partial,
                                           const float* __restrict__ u,
                                           const float* __restrict__ Wff,
                                           const float* __restrict__ bff,
                                           float* __restrict__ G) {
    int t = blockIdx.x, d = threadIdx.x;
    __shared__ __align__(16) float Ml[DD], ul[DD];
    Ml[d] = partial[t * DD + d] + partial[(size_t)TT * DD + t * DD + d]
          + partial[(size_t)2 * TT * DD + t * DD + d] + partial[(size_t)3 * TT * DD + t * DD + d];
    ul[d] = u[t * DD + d];
    __syncthreads();
    const float* wr = Wff + (size_t)d * 2 * DD;
    float a0 = 0.f, a1 = 0.f;
#pragma unroll 4
    for (int k = 0; k < DD; ++k) {
        a0 += Ml[k] * wr[k];
        a1 += ul[k] * wr[DD + k];
    }
    G[t * DD + d] = a0 + a1 + bff[d];
}

// ---------------- K5: GRU input projections (gate-interleaved layout) -------
// Writes gi[(dir*TT+t)*256 + unit*4 + gate] (gate: 0=r,1=z,2=n; slot 3 pad)
// so the scan loads one dwordx4 per unit per step.
__global__ __launch_bounds__(384) void k_gru_gi(const float* __restrict__ G,
                                                const float* __restrict__ Wf,
                                                const float* __restrict__ bf,
                                                const float* __restrict__ Wb,
                                                const float* __restrict__ bb,
                                                float* __restrict__ gi) {
    int t = blockIdx.x;
    __shared__ __align__(16) float Gl[DD];
    if (threadIdx.x < DD) Gl[threadIdx.x] = G[t * DD + threadIdx.x];
    __syncthreads();
    int r = threadIdx.x;
    int dir = r >= 192;
    int rr = dir ? r - 192 : r;
    int gate = rr >> 6, unit = rr & 63;
    const float* w = (dir ? Wb : Wf) + (size_t)rr * DD;
    float b = (dir ? bb : bf)[rr];
    float a0 = 0.f, a1 = 0.f;
#pragma unroll 4
    for (int k = 0; k < DD; k += 2) {
        a0 += Gl[k] * w[k];
        a1 += Gl[k + 1] * w[k + 1];
    }
    gi[((size_t)dir * TT + t) * 256 + unit * 4 + gate] = a0 + a1 + b;
}

// ---------------- K6: sequential BiGRU, 256 threads (4 lanes/unit) ----------
// R7 measured-best config. u=tid>>2, q=tid&3: lane owns rows {u,64+u,128+u}
// over cols [16q,16q+16) as 3 v16h regs. DPP quad reduce; hl double-buffered
// -> ONE lds_barrier/step; gi = ONE dwordx4 per step prefetched 4 ahead;
// h written TRANSPOSED (hbufT[e][t]) as float4 per 4 steps.
__global__ __launch_bounds__(256) void k_gru_seq(const float* __restrict__ Whh_f,
                                                 const float* __restrict__ bhh_f,
                                                 const float* __restrict__ Whh_b,
                                                 const float* __restrict__ bhh_b,
                                                 const float* __restrict__ gi,
                                                 float* __restrict__ hbufT) {
    int dir = blockIdx.x;
    int tid = threadIdx.x;
    int u = tid >> 2;  // 0..63
    int q = tid & 3;   // 16-col slice
    const float* Whh = dir ? Whh_b : Whh_f;
    const float* bhh = dir ? bhh_b : bhh_f;
    v16h wr = load16(Whh + (size_t)u * 64 + q * 16);
    v16h wz = load16(Whh + (size_t)(64 + u) * 64 + q * 16);
    v16h wn = load16(Whh + (size_t)(128 + u) * 64 + q * 16);
    OPAQUE3(wr, wz, wn);
    float bh_r = bhh[u], bh_z = bhh[64 + u], bh_n = bhh[128 + u];

    const float* gbase = gi + (size_t)dir * TT * 256 + u * 4;

    __shared__ __align__(16) half_t hl[2][64];
    if (tid < 64) hl[0][tid] = (half_t)0.f;
    float h = 0.f;
    // prologue: gi slots for steps 0..3 (one float4 each)
    float4 gq0, gq1, gq2, gq3;
#define GPRO(J) { \
    int tp_ = dir ? (TT - 1 - (J)) : (J); \
    gq##J = *(const float4*)(gbase + (size_t)tp_ * 256); }
    GPRO(0); GPRO(1); GPRO(2); GPRO(3);
#undef GPRO
    lds_barrier();

    float hs0 = 0.f, hs1 = 0.f, hs2 = 0.f, hs3 = 0.f;
#define GSTEP(J, HS) { \
    int s_ = s4 + (J); \
    const v8h* hv_ = (const v8h*)&hl[s_ & 1][q * 16]; \
    v8h h0_ = hv_[0], h1_ = hv_[1]; \
    float ar0 = 0.f, ar1 = 0.f, az0 = 0.f, az1 = 0.f, an0 = 0.f, an1 = 0.f; \
    dot16(wr, h0_, h1_, ar0, ar1); \
    dot16(wz, h0_, h1_, az0, az1); \
    dot16(wn, h0_, h1_, an0, an1); \
    float srd = qreduce_f(ar0 + ar1); \
    float szd = qreduce_f(az0 + az1); \
    float snd = qreduce_f(an0 + an1); \
    float r_ = sigf(gq##J.x + srd + bh_r); \
    float z_ = sigf(gq##J.y + szd + bh_z); \
    float n_ = tanhfast(gq##J.z + r_ * (snd + bh_n)); \
    h = (1.f - z_) * n_ + z_ * h; \
    if (q == 0) hl[(s_ + 1) & 1][u] = (half_t)h; \
    HS = h; \
    int sp_ = s_ + 4; if (sp_ >= TT) sp_ = TT - 1; \
    int tp_ = dir ? (TT - 1 - sp_) : sp_; \
    gq##J = *(const float4*)(gbase + (size_t)tp_ * 256); \
    lds_barrier(); }

    for (int s4 = 0; s4 < TT; s4 += 4) {
        GSTEP(0, hs0);
        GSTEP(1, hs1);
        GSTEP(2, hs2);
        GSTEP(3, hs3);
        if (q == 0) {
            float4 v;
            int tb;
            if (dir == 0) { tb = s4; v = {hs0, hs1, hs2, hs3}; }
            else          { tb = TT - 4 - s4; v = {hs3, hs2, hs1, hs0}; }
            *(float4*)(hbufT + (size_t)(dir * 64 + u) * TT + tb) = v;
        }
    }
#undef GSTEP
}

// ---------------- K7: x = embed + (u + h)@W_k.T + b_k ----------------
__global__ __launch_bounds__(512) void k_x(const float* __restrict__ u,
                                           const float* __restrict__ hbufT,
                                           const float* __restrict__ Wk,
                                           const float* __restrict__ bk,
                                           const float* __restrict__ embed,
                                           float* __restrict__ x) {
    int t = blockIdx.x, e = threadIdx.x;
    __shared__ __align__(16) float sl[DD];
    if (e < DD) sl[e] = u[t * DD + e] + hbufT[(size_t)e * TT + t];
    __syncthreads();
    const float* wr = Wk + (size_t)e * DD;
    float a0 = 0.f, a1 = 0.f;
#pragma unroll 4
    for (int k = 0; k < DD; k += 2) {
        a0 += sl[k] * wr[k];
        a1 += sl[k + 1] * wr[k + 1];
    }
    x[t * EE + e] = embed[t * EE + e] + a0 + a1 + bk[e];
}

// ---------------- K8: LSTM input projections (gate-interleaved layout) ------
__global__ __launch_bounds__(1024) void k_lstm_gi(const float* __restrict__ x,
                                                  const float* __restrict__ Wf,
                                                  const float* __restrict__ bf,
                                                  const float* __restrict__ Wb,
                                                  const float* __restrict__ bb,
                                                  float* __restrict__ gi) {
    int dir = blockIdx.y;
    int t0 = blockIdx.x * 8;
    __shared__ __align__(16) float xl[8 * EE];
    for (int i = threadIdx.x; i < 8 * EE; i += 1024) xl[i] = x[(size_t)t0 * EE + i];
    __syncthreads();
    int r = threadIdx.x;
    int gate = r >> 8, un = r & 255;
    const float* W = dir ? Wb : Wf;
    const float* bi = dir ? bb : bf;
    const float* wr = W + (size_t)r * EE;
    float b = bi[r];
    float acc[8];
#pragma unroll
    for (int uu = 0; uu < 8; ++uu) acc[uu] = b;
    for (int k = 0; k < EE; k += 4) {
        float4 wv = *(const float4*)(wr + k);
#pragma unroll
        for (int uu = 0; uu < 8; ++uu) {
            float4 xv = *(const float4*)(&xl[uu * EE + k]);
            acc[uu] += wv.x * xv.x + wv.y * xv.y + wv.z * xv.z + wv.w * xv.w;
        }
    }
#pragma unroll
    for (int uu = 0; uu < 8; ++uu)
        gi[((size_t)dir * TT + (t0 + uu)) * 1024 + un * 4 + gate] = acc[uu];
}

// ---------------- K9: sequential BiLSTM, 512 threads (2 lanes/unit) ---------
// R7 measured-best config (580us). u=tid>>1, half=tid&1: lane owns all 4
// gate rows over its 128-col half as 32 v4i int8 weights (waves_per_eu(2,2)
// -> 256-reg budget, no spill/shuttle). gi = ONE dwordx4 per step
// (gate-interleaved), prefetched 4 ahead; 128 sdot4 + DPP pair reduce; hq
// double-buffered, one lds_barrier/step; comb TRANSPOSED float4 per 4 steps.
__global__ __launch_bounds__(512) __attribute__((amdgpu_waves_per_eu(2, 2)))
void k_lstm_seq(const float* __restrict__ Whh_f,
                const float* __restrict__ bhh_f,
                const float* __restrict__ Whh_b,
                const float* __restrict__ bhh_b,
                const float* __restrict__ gi,
                float* __restrict__ combT) {
    int dir = blockIdx.x;
    int tid = threadIdx.x;
    int u = tid >> 1;      // 0..255
    int half = tid & 1;    // 128-col half
    const float* Whh = dir ? Whh_b : Whh_f;
    const float* bhh = dir ? bhh_b : bhh_f;

    __shared__ __align__(16) int hq[2][64];  // 2 x 256 int8 h buffers

    const float* ri = Whh + (size_t)u * 256 + half * 128;
    const float* rf = ri + 256 * 256;
    const float* rg = ri + 512 * 256;
    const float* ro = ri + 768 * 256;

    // full-row abs-max via own-half max + pair shfl (init-only)
    float mi = rowmax128(ri); mi = fmaxf(mi, __shfl_xor(mi, 1, 64));
    float mf = rowmax128(rf); mf = fmaxf(mf, __shfl_xor(mf, 1, 64));
    float mg = rowmax128(rg); mg = fmaxf(mg, __shfl_xor(mg, 1, 64));
    float mo = rowmax128(ro); mo = fmaxf(mo, __shfl_xor(mo, 1, 64));
    float fs_i = mi / 16129.f, fs_f = mf / 16129.f, fs_g = mg / 16129.f, fs_o = mo / 16129.f;

    float inv_i = 127.f / mi, inv_f = 127.f / mf, inv_g = 127.f / mg, inv_o = 127.f / mo;
#define DECLG(P, ptr, inv)                                                        \
    v4i P##0 = quant16((ptr), (inv)),       P##1 = quant16((ptr) + 16, (inv)),    \
        P##2 = quant16((ptr) + 32, (inv)),  P##3 = quant16((ptr) + 48, (inv)),    \
        P##4 = quant16((ptr) + 64, (inv)),  P##5 = quant16((ptr) + 80, (inv)),    \
        P##6 = quant16((ptr) + 96, (inv)),  P##7 = quant16((ptr) + 112, (inv));   \
    OPAQUE4(P##0, P##1, P##2, P##3);                                              \
    OPAQUE4(P##4, P##5, P##6, P##7)

    DECLG(wi, ri, inv_i);
    DECLG(wf, rf, inv_f);
    DECLG(wg, rg, inv_g);
    DECLG(wo, ro, inv_o);
#undef DECLG

    float bh_i = bhh[u], bh_f = bhh[256 + u], bh_g = bhh[512 + u], bh_o = bhh[768 + u];
    if (tid < 64) hq[0][tid] = 0;
    float c_state = 0.f;

    const float* gbase = gi + (size_t)dir * TT * 1024 + u * 4;

    // prologue: gi slots for steps 0..3 (one float4 each; pair lanes share)
    float4 gq0, gq1, gq2, gq3;
#define LPRO(J) { \
    int tp_ = dir ? (TT - 1 - (J)) : (J); \
    gq##J = *(const float4*)(gbase + (size_t)tp_ * 1024); }
    LPRO(0); LPRO(1); LPRO(2); LPRO(3);
#undef LPRO
    lds_barrier();

    float hs0 = 0.f, hs1 = 0.f, hs2 = 0.f, hs3 = 0.f;
#define LD1(P, C, HV, A0, A1) \
    A0 = sdot4((P##C).x, HV.x, A0); A1 = sdot4((P##C).y, HV.y, A1); \
    A0 = sdot4((P##C).z, HV.z, A0); A1 = sdot4((P##C).w, HV.w, A1)
#define LDOT8(P, A0, A1) \
    LD1(P, 0, h0_, A0, A1); LD1(P, 1, h1_, A0, A1); \
    LD1(P, 2, h2_, A0, A1); LD1(P, 3, h3_, A0, A1); \
    LD1(P, 4, h4_, A0, A1); LD1(P, 5, h5_, A0, A1); \
    LD1(P, 6, h6_, A0, A1); LD1(P, 7, h7_, A0, A1)

#define LSTEP(J, HS) { \
    int s_ = s4 + (J); \
    const v4i* hb_ = (const v4i*)&hq[s_ & 1][half * 32]; \
    v4i h0_ = hb_[0], h1_ = hb_[1], h2_ = hb_[2], h3_ = hb_[3]; \
    v4i h4_ = hb_[4], h5_ = hb_[5], h6_ = hb_[6], h7_ = hb_[7]; \
    int ai0 = 0, ai1 = 0, af0 = 0, af1 = 0, ag0 = 0, ag1 = 0, ao0 = 0, ao1 = 0; \
    LDOT8(wi, ai0, ai1); \
    LDOT8(wf, af0, af1); \
    LDOT8(wg, ag0, ag1); \
    LDOT8(wo, ao0, ao1); \
    int ai_ = preduce_i(ai0 + ai1); \
    int af_ = preduce_i(af0 + af1); \
    int ag_ = preduce_i(ag0 + ag1); \
    int ao_ = preduce_i(ao0 + ao1); \
    float iv = sigf((float)ai_ * fs_i + bh_i + gq##J.x); \
    float fv = sigf((float)af_ * fs_f + bh_f + gq##J.y); \
    float gv = tanhfast((float)ag_ * fs_g + bh_g + gq##J.z); \
    float ov = sigf((float)ao_ * fs_o + bh_o + gq##J.w); \
    c_state = fv * c_state + iv * gv; \
    HS = ov * tanhfast(c_state); \
    if (half == 0) ((signed char*)hq[(s_ + 1) & 1])[u] = (signed char)__float2int_rn(HS * 127.f); \
    int sp_ = s_ + 4; if (sp_ >= TT) sp_ = TT - 1; \
    int tp_ = dir ? (TT - 1 - sp_) : sp_; \
    gq##J = *(const float4*)(gbase + (size_t)tp_ * 1024); \
    lds_barrier(); }

    for (int s4 = 0; s4 < TT; s4 += 4) {
        LSTEP(0, hs0);
        LSTEP(1, hs1);
        LSTEP(2, hs2);
        LSTEP(3, hs3);
        if (half == 0) {
            float4 v;
            int tb;
            if (dir == 0) { tb = s4; v = {hs0, hs1, hs2, hs3}; }
            else          { tb = TT - 4 - s4; v = {hs3, hs2, hs1, hs0}; }
            *(float4*)(combT + (size_t)(dir * 256 + u) * TT + tb) = v;
        }
    }
#undef LSTEP
#undef LDOT8
#undef LD1
}

// ---------------- K10: logits + softmax ----------------
__global__ __launch_bounds__(128) void k_out(const float* __restrict__ combT,
                                             const float* __restrict__ Wout,
                                             const float* __restrict__ bout,
                                             float* __restrict__ out) {
    int t = blockIdx.x;
    __shared__ __align__(16) float cl[EE];
    __shared__ float ll[NTAGS];
    __shared__ float mred, sred;
    for (int i = threadIdx.x; i < EE; i += 128) cl[i] = combT[(size_t)i * TT + t];
    __syncthreads();
    int e = threadIdx.x;
    if (e < NTAGS) {
        const float* wr = Wout + (size_t)e * EE;
        float a0 = 0.f, a1 = 0.f;
#pragma unroll 4
        for (int k = 0; k < EE; k += 2) {
            a0 += cl[k] * wr[k];
            a1 += cl[k + 1] * wr[k + 1];
        }
        ll[e] = a0 + a1 + bout[e];
    }
    __syncthreads();
    if (threadIdx.x == 0) {
        float m = ll[0];
        for (int i = 1; i < NTAGS; ++i) m = fmaxf(m, ll[i]);
        float ss = 0.f;
        for (int i = 0; i < NTAGS; ++i) ss += __expf(ll[i] - m);
        mred = m;
        sred = ss;
    }
    __syncthreads();
    if (e < NTAGS) out[t * NTAGS + e] = __expf(ll[e] - mred) / sred;
}

// ---------------- workspace layout (floats) ----------------
// wsum partials [4][TT*DD] live in the giL slot (giL is written much later
// by k_lstm_gi, consumed by k_lstm_seq; partials dead after k_G).
// giG [2][512][256] lives in the combT slot (dead after k_gru_seq).
#define OFF_DOTS  ((size_t)0)
#define OFF_P     ((size_t)512)
#define OFF_G     ((size_t)66560)
#define OFF_HBUF  ((size_t)328704)   // hbufT [128][512]
#define OFF_X     ((size_t)394240)   // [512][512]
#define OFF_GIL   ((size_t)656384)   // [2][512][1024]; also wsum partials
#define OFF_COMB  ((size_t)1704960)  // combT [512][512]
#define OFF_GIG   OFF_COMB           // giG [2][512][256] (disjoint lifetime)
#define OFF_WPART OFF_GIL            // [4][TT*DD] (disjoint lifetime)

extern "C" void kernel_launch(void* const* d_in, const int* in_sizes, int n_in,
                              void* d_out, int out_size, void* d_ws, size_t ws_size,
                              hipStream_t stream) {
    const float* memory = (const float*)d_in[0];
    const float* u      = (const float*)d_in[1];
    const float* embed  = (const float*)d_in[2];
    const float* W_ff   = (const float*)d_in[3];
    const float* b_ff   = (const float*)d_in[4];
    const float* gWih_f = (const float*)d_in[5];
    const float* gWhh_f = (const float*)d_in[6];
    const float* gbih_f = (const float*)d_in[7];
    const float* gbhh_f = (const float*)d_in[8];
    const float* gWih_b = (const float*)d_in[9];
    const float* gWhh_b = (const float*)d_in[10];
    const float* gbih_b = (const float*)d_in[11];
    const float* gbhh_b = (const float*)d_in[12];
    const float* W_k    = (const float*)d_in[13];
    const float* b_k    = (const float*)d_in[14];
    const float* lWih_f = (const float*)d_in[15];
    const float* lWhh_f = (const float*)d_in[16];
    const float* lbih_f = (const float*)d_in[17];
    const float* lbhh_f = (const float*)d_in[18];
    const float* lWih_b = (const float*)d_in[19];
    const float* lWhh_b = (const float*)d_in[20];
    const float* lbih_b = (const float*)d_in[21];
    const float* lbhh_b = (const float*)d_in[22];
    const float* W_out  = (const float*)d_in[23];
    const float* b_out  = (const float*)d_in[24];
    float* out = (float*)d_out;
    float* ws = (float*)d_ws;

    float* dots  = ws + OFF_DOTS;
    float* p     = ws + OFF_P;
    float* wpart = ws + OFF_WPART;
    float* G     = ws + OFF_G;
    float* giG   = ws + OFF_GIG;
    float* hbufT = ws + OFF_HBUF;
    float* x     = ws + OFF_X;
    float* giL   = ws + OFF_GIL;
    float* combT = ws + OFF_COMB;

    k_dots<<<MM, 256, 0, stream>>>(memory, u, dots);
    k_softmax_p<<<1, MM, 0, stream>>>(dots, p);
    k_wsum4<<<dim3(128, 4), 128, 0, stream>>>(memory, p, wpart);
    k_G<<<TT, DD, 0, stream>>>(wpart, u, W_ff, b_ff, G);
    k_gru_gi<<<TT, 384, 0, stream>>>(G, gWih_f, gbih_f, gWih_b, gbih_b, giG);
    k_gru_seq<<<2, 256, 0, stream>>>(gWhh_f, gbhh_f, gWhh_b, gbhh_b, giG, hbufT);
    k_x<<<TT, EE, 0, stream>>>(u, hbufT, W_k, b_k, embed, x);
    k_lstm_gi<<<dim3(64, 2), 1024, 0, stream>>>(x, lWih_f, lbih_f, lWih_b, lbih_b, giL);
    k_lstm_seq<<<2, 512, 0, stream>>>(lWhh_f, lbhh_f, lWhh_b, lbhh_b, giL, combT);
    k_out<<<TT, 128, 0, stream>>>(combT, W_out, b_out, out);
}